// Round 1
// baseline (1388.589 us; speedup 1.0000x reference)
//
#include <hip/hip_runtime.h>
#include <math.h>

// Problem constants
#define DD 256            // latent dim
#define KK 8192           // codebook size
#define NN 16384          // rows
#define MT 32             // rows per block (shared by both chunk-groups)
#define RPW 8             // rows per wave (keeps fma:overhead ratio)
#define NT 512            // codebook cols per chunk (lane + 64*j, j 0..7)
#define NCHG 8            // chunks per group (16 total / 2 groups)
#define DT 4              // d-slice floats per epoch (1 d4-step)
#define NSL (DD / DT)     // 64 slices per chunk
#define NEPG (NCHG * NSL) // 512 epochs per group
#define NBLOCKS (NN / MT) // 512 blocks x 512 threads -> 2 blocks/CU, 4 waves/SIMD
#define CBUFF 2048        // floats per C buffer (512 cols x 4 d) = 8 KB
#define RSTRIDE 260       // rowsumsq staging stride (unchanged, verified)

// Output layout (all float32, concatenated in reference return order)
#define OUT_IDS   0
#define OUT_Q     16384
#define OUT_ST    4210688          // 16384 + 4194304
#define OUT_COMMIT 8404992
#define OUT_CBL    8404993
#define OUT_PERP   8404994

// ---------------------------------------------------------------------------
// async global->LDS DMA: lane i's 16B lands at ldsbase + i*16 (contiguous 1KB).
// Global source address is PER-LANE -> layout shuffles live on the source side.
// ---------------------------------------------------------------------------
__device__ __forceinline__ void gl2lds16(const float* g, float* l) {
    __builtin_amdgcn_global_load_lds(
        (const __attribute__((address_space(1))) float*)g,
        (__attribute__((address_space(3))) float*)l, 16, 0, 0);
}

// readlane: pull a float from a given lane into an SGPR (uniform). Bit-exact.
__device__ __forceinline__ float rlane(float v, int l) {
    return __int_as_float(__builtin_amdgcn_readlane(__float_as_int(v), l));
}

// ---------------------------------------------------------------------------
// numpy pairwise-sum replica for sum of squares (verified bit-exact, round 2)
// ---------------------------------------------------------------------------
__device__ __forceinline__ float np_block128_sumsq(const float* p) {
    #pragma clang fp contract(off)
    float r0 = p[0] * p[0], r1 = p[1] * p[1], r2 = p[2] * p[2], r3 = p[3] * p[3];
    float r4 = p[4] * p[4], r5 = p[5] * p[5], r6 = p[6] * p[6], r7 = p[7] * p[7];
    for (int i = 8; i < 128; i += 8) {
        r0 = r0 + p[i + 0] * p[i + 0];
        r1 = r1 + p[i + 1] * p[i + 1];
        r2 = r2 + p[i + 2] * p[i + 2];
        r3 = r3 + p[i + 3] * p[i + 3];
        r4 = r4 + p[i + 4] * p[i + 4];
        r5 = r5 + p[i + 5] * p[i + 5];
        r6 = r6 + p[i + 6] * p[i + 6];
        r7 = r7 + p[i + 7] * p[i + 7];
    }
    return ((r0 + r1) + (r2 + r3)) + ((r4 + r5) + (r6 + r7));
}

__device__ __forceinline__ float np_pairwise256_sumsq(const float* a) {
    #pragma clang fp contract(off)
    float s0 = np_block128_sumsq(a);
    float s1 = np_block128_sumsq(a + 128);
    return s0 + s1;
}

// ---------------------------------------------------------------------------
// Kernel 1: per-row sum of squares, numpy-pairwise-exact (unchanged, verified)
// ---------------------------------------------------------------------------
__global__ __launch_bounds__(256) void rowsumsq(const float* __restrict__ A,
                                                float* __restrict__ out) {
    __shared__ __align__(16) float sA[64][RSTRIDE];
    const int tid = threadIdx.x;
    const int base = blockIdx.x * 64;
    #pragma unroll
    for (int i = 0; i < 16; ++i) {
        int g = i * 256 + tid;
        int row = g >> 6, d4 = g & 63;
        float4 v = reinterpret_cast<const float4*>(A)[(size_t)(base + row) * (DD / 4) + d4];
        *reinterpret_cast<float4*>(&sA[row][d4 * 4]) = v;
    }
    __syncthreads();
    if (tid < 64) out[base + tid] = np_pairwise256_sumsq(sA[tid]);
}

// ---------------------------------------------------------------------------
// Kernel 2: main VQ kernel. 512 blocks x 512 threads, 2 blocks/CU.
//   NEW (this round): K-split into 2 chunk-groups of 4 waves each.
//   Group g scans chunks g*8..g*8+7 (cols g*4096..g*4096+4095) over the SAME
//   32 rows; sX (32 KB) is shared, each group has a private double-buffered
//   8 KB C stream (DT=4). Both groups iterate slices in lockstep, so the
//   block-wide __syncthreads points coincide. This doubles resident waves
//   (8->16 per CU, 2->4 per SIMD) without touching the per-(row,col) fp32
//   fma chain (d = 0..255, x/y/z/w order) -> scores stay bit-exact.
//   Cross-group argmin merge: group 0 owns lower col indices, so strict-less
//   from group 1 preserves global first-index tie semantics.
// ---------------------------------------------------------------------------
__global__ __launch_bounds__(512, 4) void vq_main(const float* __restrict__ X,
                                                  const float* __restrict__ CB,
                                                  const float* __restrict__ c2,
                                                  const float* __restrict__ x2,
                                                  const float* __restrict__ mask,
                                                  float* __restrict__ out,
                                                  float* __restrict__ hist,
                                                  float* __restrict__ partial) {
    __shared__ __align__(16) float sX[8192];        // 32 KB: 32 rows x 256 d (shared)
    __shared__ __align__(16) float sC[4 * CBUFF];   // 32 KB: 2 groups x dbuf x 8 KB
    __shared__ float gbest[2][MT];
    __shared__ int   gidx[2][MT];
    __shared__ int   row_id[MT];
    __shared__ float wsum[4];

    const int tid  = threadIdx.x;
    const int lane = tid & 63;
    const int wid  = tid >> 6;                                  // 0..7
    const int widu = __builtin_amdgcn_readfirstlane(wid);       // uniform copy
    const int g    = wid >> 2;        // chunk-group (0: cols 0..4095, 1: 4096..8191)
    const int gu   = widu >> 2;
    const int wg   = wid & 3;         // row-group within block (8 rows each)
    const int wgu  = widu & 3;
    const int block_row = blockIdx.x * MT;

    // ---- stage X (32 rows x 256 d = 32 KB): 4 superblocks per wave.
    //      Superblock (r8, kk) holds rows r8*8..+7 x d4 kk*8..+7; staging lane L
    //      writes unit L = (d4rel=L>>3, rr=L&7) -> compute read is lane-linear.
    {
        const unsigned rr = lane & 7u, d4r = lane >> 3;
        const int r8 = widu >> 1, h = widu & 1;
        #pragma unroll
        for (int k = 0; k < 4; ++k) {
            const int kk = h * 4 + k;
            gl2lds16(X + (size_t)(block_row + r8 * 8 + rr) * DD + kk * 32 + d4r * 4,
                     &sX[(r8 * 8 + kk) * 256]);
        }
    }

    // ---- C staging source offsets: unit u = col (single d4-plane), 2 calls/wave ----
    unsigned coff[2];
    #pragma unroll
    for (int k = 0; k < 2; ++k)
        coff[k] = ((wgu * 2u + (unsigned)k) * 64u + (unsigned)lane) * DD;

    const float* CBg = CB + (size_t)gu * NCHG * NT * DD;   // group's chunk base
    float* sCg = &sC[gu * 2 * CBUFF];                      // group's buffer pair
    #pragma unroll
    for (int k = 0; k < 2; ++k)     // epoch 0 (group chunk 0, sl 0) -> buf 0
        gl2lds16(CBg + coff[k], sCg + (wgu * 2 + k) * 256);

    // row constants (bit-identical to numpy's x2)
    float x2r[RPW];
    #pragma unroll
    for (int rr = 0; rr < RPW; ++rr) x2r[rr] = x2[block_row + wg * RPW + rr];

    __syncthreads();   // drains vmcnt -> sX + both groups' buf0 resident

    float best[RPW];
    int   besti[RPW];
    #pragma unroll
    for (int rr = 0; rr < RPW; ++rr) { best[rr] = 3.4e38f; besti[rr] = 0; }

    for (int ch = 0; ch < NCHG; ++ch) {
        const int chg = g * NCHG + ch;                 // global chunk id
        float c2v[8];
        #pragma unroll
        for (int j = 0; j < 8; ++j) c2v[j] = c2[chg * NT + lane + 64 * j];

        float acc[8][8];
        #pragma unroll
        for (int rr = 0; rr < 8; ++rr)
            #pragma unroll
            for (int j = 0; j < 8; ++j) acc[rr][j] = 0.0f;

        float4 xp;   // current X super-block (reloaded every 8 slices)

        #pragma unroll 8
        for (int sl = 0; sl < NSL; ++sl) {
            const int e = ch * NSL + sl;

            // ---- async-stage next C slice (group-private stream) ----
            if (e + 1 < NEPG) {
                const int nch = (e + 1) >> 6, nsl = (e + 1) & 63;
                const float* so = CBg + (size_t)nch * (NT * DD) + nsl * DT;
                float* dst = sCg + ((e + 1) & 1) * CBUFF;
                #pragma unroll
                for (int k = 0; k < 2; ++k)
                    gl2lds16(so + coff[k], dst + (wgu * 2 + k) * 256);
            }

            // ---- X super-block: one b128 per 8 slices ----
            if ((sl & 7) == 0)
                xp = *reinterpret_cast<const float4*>(
                        &sX[(wg * 8 + (sl >> 3)) * 256 + lane * 4]);

            // ---- compute: 1 d4-step on current buffer ----
            const int t = sl & 7;                     // d4 within super-block
            const float* cb_ = sCg + (e & 1) * CBUFF + lane * 4;
            float4 cc[8];
            #pragma unroll
            for (int j = 0; j < 8; ++j)
                cc[j] = *reinterpret_cast<const float4*>(cb_ + j * 256);
            #pragma unroll
            for (int rr = 0; rr < 8; ++rr) {
                const int rl = t * 8 + rr;            // lane holding X[rr][d4]
                const float sx = rlane(xp.x, rl);
                const float sy = rlane(xp.y, rl);
                const float sz = rlane(xp.z, rl);
                const float sw = rlane(xp.w, rl);
                #pragma unroll
                for (int j = 0; j < 8; ++j) {
                    acc[rr][j] = fmaf(sx, cc[j].x, acc[rr][j]);
                    acc[rr][j] = fmaf(sy, cc[j].y, acc[rr][j]);
                    acc[rr][j] = fmaf(sz, cc[j].z, acc[rr][j]);
                    acc[rr][j] = fmaf(sw, cc[j].w, acc[rr][j]);
                }
            }
            __syncthreads();   // reads of cur buf done; next-slice DMA drained
        }

        // ---- fp32 distance exactly as numpy, then argmin (first-index ties) ----
        #pragma unroll
        for (int rr = 0; rr < 8; ++rr) {
            #pragma unroll
            for (int j = 0; j < 8; ++j) {
                const int col = chg * NT + lane + 64 * j;
                float t1 = x2r[rr] + c2v[j];
                float sc = t1 - 2.0f * acc[rr][j];
                if (sc < best[rr] || (sc == best[rr] && col < besti[rr])) {
                    best[rr] = sc; besti[rr] = col;
                }
            }
        }
    }

    // ---- per-row argmin across the wave's 64 lanes (xor butterfly) ----
    #pragma unroll
    for (int rr = 0; rr < RPW; ++rr) {
        float b = best[rr];
        int  bi = besti[rr];
        #pragma unroll
        for (int m = 32; m > 0; m >>= 1) {
            float b2 = __shfl_xor(b, m, 64);
            int   i2 = __shfl_xor(bi, m, 64);
            if (b2 < b || (b2 == b && i2 < bi)) { b = b2; bi = i2; }
        }
        if (lane == 0) {
            gbest[g][wg * RPW + rr] = b;
            gidx [g][wg * RPW + rr] = bi;
        }
    }
    __syncthreads();

    // ---- cross-group merge: group 0 has lower cols, so tie -> group 0 ----
    if (tid < MT) {
        const float b0 = gbest[0][tid], b1 = gbest[1][tid];
        const int bi = (b1 < b0) ? gidx[1][tid] : gidx[0][tid];
        row_id[tid] = bi;
        out[OUT_IDS + block_row + tid] = (float)bi;
        atomicAdd(&hist[bi], mask[block_row + tid]);
    }
    __syncthreads();

    // ---- fused gather: quantized, st_quantized, MSE partial.
    //      Kept VERBATIM on tid<256 so every partial-sum rounding is
    //      bit-identical to the previously verified kernel. ----
    if (tid < 256) {
        float msep = 0.0f;
        float* outq  = out + OUT_Q;
        float* outst = out + OUT_ST;
        #pragma unroll
        for (int i = 0; i < 8; ++i) {
            int g2 = i * 256 + tid;         // 0..2047 covers 32 rows x 64 float4
            int row = g2 >> 6;
            int d4  = g2 & 63;
            int id  = row_id[row];
            float4 q = reinterpret_cast<const float4*>(CB)[(size_t)id * (DD / 4) + d4];
            float4 x = reinterpret_cast<const float4*>(X)[(size_t)(block_row + row) * (DD / 4) + d4];
            float4 st;
            st.x = x.x + (q.x - x.x);
            st.y = x.y + (q.y - x.y);
            st.z = x.z + (q.z - x.z);
            st.w = x.w + (q.w - x.w);
            float dx = x.x - q.x; msep = fmaf(dx, dx, msep);
            dx = x.y - q.y; msep = fmaf(dx, dx, msep);
            dx = x.z - q.z; msep = fmaf(dx, dx, msep);
            dx = x.w - q.w; msep = fmaf(dx, dx, msep);
            size_t o = (size_t)(block_row + row) * (DD / 4) + d4;
            reinterpret_cast<float4*>(outq)[o]  = q;
            reinterpret_cast<float4*>(outst)[o] = st;
        }
        #pragma unroll
        for (int off = 32; off > 0; off >>= 1) msep += __shfl_down(msep, off, 64);
        if (lane == 0) wsum[wid] = msep;
    }
    __syncthreads();
    if (tid == 0) partial[blockIdx.x] = wsum[0] + wsum[1] + wsum[2] + wsum[3];
}

// ---------------------------------------------------------------------------
// Kernel 3: finalize losses + perplexity (double precision, single block)
// ---------------------------------------------------------------------------
__global__ __launch_bounds__(256) void vq_finalize(const float* __restrict__ partial,
                                                   const float* __restrict__ hist,
                                                   float* __restrict__ out) {
    __shared__ double red[256];
    const int tid = threadIdx.x;

    double ps = 0.0;
    for (int j = tid; j < NBLOCKS; j += 256) ps += (double)partial[j];
    red[tid] = ps;
    __syncthreads();
    for (int s = 128; s > 0; s >>= 1) {
        if (tid < s) red[tid] += red[tid + s];
        __syncthreads();
    }
    double mse_sum = red[0];
    __syncthreads();

    double hs = 0.0;
    for (int j = tid; j < KK; j += 256) hs += (double)hist[j];
    red[tid] = hs;
    __syncthreads();
    for (int s = 128; s > 0; s >>= 1) {
        if (tid < s) red[tid] += red[tid + s];
        __syncthreads();
    }
    double denom = red[0] > 1.0 ? red[0] : 1.0;
    __syncthreads();

    double ent = 0.0;
    for (int j = tid; j < KK; j += 256) {
        double p = (double)hist[j] / denom;
        ent += p * log(p + 1e-8);
    }
    red[tid] = ent;
    __syncthreads();
    for (int s = 128; s > 0; s >>= 1) {
        if (tid < s) red[tid] += red[tid + s];
        __syncthreads();
    }

    if (tid == 0) {
        double mse = mse_sum / (double)((size_t)NN * DD);
        out[OUT_COMMIT] = (float)(mse * 0.25);
        out[OUT_CBL]    = (float)mse;
        out[OUT_PERP]   = (float)exp(-red[0]);
    }
}

// ---------------------------------------------------------------------------
extern "C" void kernel_launch(void* const* d_in, const int* in_sizes, int n_in,
                              void* d_out, int out_size, void* d_ws, size_t ws_size,
                              hipStream_t stream) {
    const float* latents = (const float*)d_in[0];   // [16,1024,256]
    const float* mask    = (const float*)d_in[1];   // [16,1024]
    const float* cb      = (const float*)d_in[2];   // [8192,256]
    float* out = (float*)d_out;

    // workspace layout (floats): hist[8192] | partial[512] | c2[8192] | x2[16384]
    float* hist    = (float*)d_ws;
    float* partial = hist + KK;
    float* c2      = partial + NBLOCKS;
    float* x2      = c2 + KK;

    hipMemsetAsync(d_ws, 0, KK * sizeof(float), stream);   // zero histogram
    rowsumsq<<<KK / 64, 256, 0, stream>>>(cb, c2);          // numpy-exact |c|^2
    rowsumsq<<<NN / 64, 256, 0, stream>>>(latents, x2);     // numpy-exact |x|^2
    vq_main<<<NBLOCKS, 512, 0, stream>>>(latents, cb, c2, x2, mask, out, hist, partial);
    vq_finalize<<<1, 256, 0, stream>>>(partial, hist, out);
}